// Round 8
// baseline (1247.346 us; speedup 1.0000x reference)
//
#include <hip/hip_runtime.h>
#include <hip/hip_bf16.h>

#define U_CNT 100000
#define I_CNT 50000
#define N_CNT 150000
#define NNZ_CNT 6000000
#define BKT_ROWS 128
#define NBKT 1172                 // ceil(150000/128)
#define OFFW (NBKT + 1)           // 1173
#define CHUNK 4096
#define NBLK_BIN 1465             // ceil(6M/4096)
#define COL_MASK 0x3FFFF          // 18 bits (N=150000 < 2^18)

// ---------------------------------------------------------------------------
// bin_sort: per-block LDS counting sort by bucket (row>>7); writes the block's
// 4096 records BLOCK-MAJOR into a private contiguous 32KB region -> full-line,
// write-once, zero RMW amplification. offM[g][b] = abs start of block g's
// bucket-b segment (sentinel at b=NBKT).
// ---------------------------------------------------------------------------
__global__ __launch_bounds__(1024) void bin_sort_kernel(
    const int* __restrict__ erow, const int* __restrict__ ecol,
    const float* __restrict__ evalv,
    int2* __restrict__ recs_bm, int* __restrict__ offM)
{
    __shared__ int2 stage[CHUNK];       // 32 KB; low 8KB reused as scan temp
    __shared__ int  hist[NBKT];
    __shared__ int  lbase[NBKT];

    int t = threadIdx.x;
    int g = blockIdx.x;
    int base = g * CHUNK;
    int n = NNZ_CNT - base; if (n > CHUNK) n = CHUNK;

    int rows[4], cols[4]; float vals[4];
#pragma unroll
    for (int k = 0; k < 4; ++k) {
        int e = base + k * 1024 + t;
        bool ok = (e < NNZ_CNT);
        rows[k] = ok ? erow[e] : -1;
        cols[k] = ok ? ecol[e] : 0;
        vals[k] = ok ? evalv[e] : 0.f;
    }

    for (int i = t; i < NBKT; i += 1024) hist[i] = 0;
    __syncthreads();
#pragma unroll
    for (int k = 0; k < 4; ++k)
        if (rows[k] >= 0) atomicAdd(&hist[rows[k] >> 7], 1);
    __syncthreads();

    // exclusive scan of hist (2048-wide two-half Hillis in stage temp)
    int* sc = (int*)stage;
    int v0 = (t < NBKT) ? hist[t] : 0;
    int v1 = (1024 + t < NBKT) ? hist[1024 + t] : 0;
    sc[t] = v0; sc[1024 + t] = v1;
    __syncthreads();
    for (int off = 1; off < 1024; off <<= 1) {
        int u0 = (t >= off) ? sc[t - off] : 0;
        int u1 = (t >= off) ? sc[1024 + t - off] : 0;
        __syncthreads();
        sc[t] += u0; sc[1024 + t] += u1;
        __syncthreads();
    }
    int tot0 = sc[1023];
    if (t < NBKT) lbase[t] = sc[t] - v0;
    if (1024 + t < NBKT) lbase[1024 + t] = tot0 + sc[1024 + t] - v1;
    __syncthreads();

    // reset hist as scatter cursors
    for (int i = t; i < NBKT; i += 1024) hist[i] = 0;
    __syncthreads();

    // scatter into LDS stage (bucket-major within block)
#pragma unroll
    for (int k = 0; k < 4; ++k) {
        if (rows[k] >= 0) {
            int b = rows[k] >> 7;
            int p = lbase[b] + atomicAdd(&hist[b], 1);
            int pack = ((rows[k] & (BKT_ROWS - 1)) << 18) | cols[k];
            stage[p] = make_int2(pack, __float_as_int(vals[k]));
        }
    }
    __syncthreads();

    // stream out block's private region (coalesced, full lines, write-once)
    for (int i = t; i < n; i += 1024) recs_bm[base + i] = stage[i];

    // per-block bucket offsets
    for (int i = t; i < NBKT; i += 1024)
        offM[(size_t)g * OFFW + i] = base + lbase[i];
    if (t == 0) offM[(size_t)g * OFFW + NBKT] = base + n;
}

// ---------------------------------------------------------------------------
// row_hist: block = bucket; count rows by scanning the bucket's 1465 segments
// directly from block-major records (L2/L3-resident). LDS atomics only.
// ---------------------------------------------------------------------------
__global__ __launch_bounds__(1024) void row_hist_kernel(
    const int2* __restrict__ recs_bm, const int* __restrict__ offM,
    int* __restrict__ cnt)
{
    __shared__ int lcnt[BKT_ROWS];
    int b = blockIdx.x;
    int t = threadIdx.x;
    if (t < BKT_ROWS) lcnt[t] = 0;
    __syncthreads();
    int wid = t >> 6, lane = t & 63;
    for (int g = wid; g < NBLK_BIN; g += 16) {
        size_t o = (size_t)g * OFFW + b;
        int s = offM[o], e = offM[o + 1];
        for (int i = s + lane; i < e; i += 64)
            atomicAdd(&lcnt[recs_bm[i].x >> 18], 1);
    }
    __syncthreads();
    int rowbase = b << 7;
    if (t < BKT_ROWS && rowbase + t < N_CNT) cnt[rowbase + t] = lcnt[t];
}

// ---------------------------------------------------------------------------
// 2-level exclusive scan over row counts -> rp
// ---------------------------------------------------------------------------
__global__ void scan_block_kernel(const int* __restrict__ in, int* __restrict__ out,
                                  int* __restrict__ bsum, int n) {
    __shared__ int sm[1024];
    int t = threadIdx.x;
    int i = blockIdx.x * 1024 + t;
    int v = (i < n) ? in[i] : 0;
    sm[t] = v;
    __syncthreads();
    for (int off = 1; off < 1024; off <<= 1) {
        int u = (t >= off) ? sm[t - off] : 0;
        __syncthreads();
        sm[t] += u;
        __syncthreads();
    }
    if (i < n) out[i] = sm[t] - v;
    if (t == 1023 && bsum) bsum[blockIdx.x] = sm[1023];
}

__global__ void scan_fix_kernel(int* __restrict__ rp, const int* __restrict__ boff,
                                int n, int nnz) {
    int i = blockIdx.x * 1024 + threadIdx.x;
    if (i < n) rp[i] += boff[blockIdx.x];
    if (i == 0) rp[n] = nnz;
}

// ---------------------------------------------------------------------------
// place: block = bucket; read segments directly, LDS row cursors, write CSR
// pairs with PRE-SCALED col byte-offsets (col<<8) for cheap gather addressing.
// Destination = block-exclusive contiguous ~41KB region of `pairs`.
// ---------------------------------------------------------------------------
__global__ __launch_bounds__(1024) void place_kernel(
    const int2* __restrict__ recs_bm, const int* __restrict__ offM,
    const int* __restrict__ rp, int2* __restrict__ pairs)
{
    __shared__ int cur[BKT_ROWS];
    int b = blockIdx.x;
    int t = threadIdx.x;
    int rowbase = b << 7;
    if (t < BKT_ROWS) cur[t] = (rowbase + t < N_CNT) ? rp[rowbase + t] : 0;
    __syncthreads();
    int wid = t >> 6, lane = t & 63;
    for (int g = wid; g < NBLK_BIN; g += 16) {
        size_t o = (size_t)g * OFFW + b;
        int s = offM[o], e = offM[o + 1];
        for (int i = s + lane; i < e; i += 64) {
            int2 r = recs_bm[i];
            int p = atomicAdd(&cur[r.x >> 18], 1);
            pairs[p] = make_int2((r.x & COL_MASK) << 8, r.y);  // byte offset
        }
    }
}

// ---------------------------------------------------------------------------
// SpMM: wave per row, lane = feature dim. Single uniform x base (SGPR) +
// 32-bit pre-scaled voffset: addr = x + (p.x | lane*4) -> 1 VALU op/edge.
// mode: 0 = y & acc=, 1 = y & acc+=, 2 = acc+= only (dead y skipped).
// ---------------------------------------------------------------------------
__global__ __launch_bounds__(256) void spmm_kernel(
    const int* __restrict__ rp, const int2* __restrict__ pairs,
    const float* __restrict__ x, float* __restrict__ y,
    float* __restrict__ acc, int mode)
{
    int wave = threadIdx.x >> 6;
    int lane = threadIdx.x & 63;
    int row = blockIdx.x * 4 + wave;
    if (row >= N_CNT) return;
    int s = rp[row];
    int e = rp[row + 1];
    const char* xb = (const char*)x;
    unsigned lane4 = (unsigned)(lane << 2);
    float sum = 0.f;
    int i = s;
    for (; i + 7 < e; i += 8) {
        int2 p[8];
#pragma unroll
        for (int k = 0; k < 8; ++k) p[k] = pairs[i + k];
        float a[8];
#pragma unroll
        for (int k = 0; k < 8; ++k)
            a[k] = *(const float*)(xb + ((unsigned)p[k].x | lane4));
#pragma unroll
        for (int k = 0; k < 8; ++k)
            sum = fmaf(__int_as_float(p[k].y), a[k], sum);
    }
    for (; i < e; ++i) {
        int2 pk = pairs[i];
        sum = fmaf(__int_as_float(pk.y),
                   *(const float*)(xb + ((unsigned)pk.x | lane4)), sum);
    }
    size_t o = (size_t)row * 64 + lane;
    if (mode == 0)      { y[o] = sum; acc[o] = sum; }
    else if (mode == 1) { y[o] = sum; acc[o] += sum; }
    else                {             acc[o] += sum; }
}

// ---------------------------------------------------------------------------
// Fused dual 2-layer MLP: per row computes BOTH the shared head and the
// user/item head (4 weight matrices transposed in LDS, 64KB -> 2 blocks/CU).
// Reads acc once. out_x offset formula is XB + r*64 for both row ranges.
// ---------------------------------------------------------------------------
__global__ __launch_bounds__(256) void mlp_dual_kernel(
    const float* __restrict__ acc, int row_s, int row_e, float scale,
    const float* __restrict__ Ws1, const float* __restrict__ bs1,
    const float* __restrict__ Ws2, const float* __restrict__ bs2,
    const float* __restrict__ Wx1, const float* __restrict__ bx1,
    const float* __restrict__ Wx2, const float* __restrict__ bx2,
    float* __restrict__ out_s, float* __restrict__ out_x)
{
    __shared__ float S1[4096], S2[4096], X1[4096], X2[4096];
    __shared__ float rbuf[4][64], h1buf[4][64], h2buf[4][64];

    int t = threadIdx.x;
    for (int idx = t; idx < 4096; idx += 256) {
        int k = idx >> 6, d = idx & 63;
        S1[idx] = Ws1[d * 64 + k];
        S2[idx] = Ws2[d * 64 + k];
        X1[idx] = Wx1[d * 64 + k];
        X2[idx] = Wx2[d * 64 + k];
    }
    __syncthreads();

    int wave = t >> 6, lane = t & 63;
    float vbs1 = bs1[lane], vbs2 = bs2[lane];
    float vbx1 = bx1[lane], vbx2 = bx2[lane];

    for (int r = row_s + blockIdx.x * 4 + wave; r < row_e; r += gridDim.x * 4) {
        float xv = acc[(size_t)r * 64 + lane] * scale;
        rbuf[wave][lane] = xv;           // same-wave write/read: no barrier needed
        float h1 = vbs1, h2 = vbx1;
#pragma unroll
        for (int k = 0; k < 64; ++k) {
            float rv = rbuf[wave][k];
            h1 = fmaf(rv, S1[k * 64 + lane], h1);
            h2 = fmaf(rv, X1[k * 64 + lane], h2);
        }
        h1 = fmaxf(h1, 0.f);
        h2 = fmaxf(h2, 0.f);
        h1buf[wave][lane] = h1;
        h2buf[wave][lane] = h2;
        float y1 = vbs2, y2 = vbx2;
#pragma unroll
        for (int k = 0; k < 64; ++k) {
            y1 = fmaf(h1buf[wave][k], S2[k * 64 + lane], y1);
            y2 = fmaf(h2buf[wave][k], X2[k * 64 + lane], y2);
        }
        out_s[(size_t)r * 64 + lane] = y1;
        out_x[(size_t)r * 64 + lane] = y2;
    }
}

// ---------------------------------------------------------------------------

static inline int imin(int a, int b) { return a < b ? a : b; }

extern "C" void kernel_launch(void* const* d_in, const int* in_sizes, int n_in,
                              void* d_out, int out_size, void* d_ws, size_t ws_size,
                              hipStream_t stream)
{
    (void)in_sizes; (void)n_in; (void)out_size; (void)ws_size;

    const float* user_emb = (const float*)d_in[0];
    const float* item_emb = (const float*)d_in[1];
    const int*   erow     = (const int*)d_in[2];
    const int*   ecol     = (const int*)d_in[3];
    const float* evalv    = (const float*)d_in[4];
    const float* Wsg1 = (const float*)d_in[5];
    const float* bsg1 = (const float*)d_in[6];
    const float* Wsg2 = (const float*)d_in[7];
    const float* bsg2 = (const float*)d_in[8];
    const float* Wuf1 = (const float*)d_in[9];
    const float* buf1 = (const float*)d_in[10];
    const float* Wuf2 = (const float*)d_in[11];
    const float* buf2 = (const float*)d_in[12];
    const float* Wif1 = (const float*)d_in[13];
    const float* bif1 = (const float*)d_in[14];
    const float* Wif2 = (const float*)d_in[15];
    const float* bif2 = (const float*)d_in[16];

    float* out = (float*)d_out;
    const size_t XB = (size_t)N_CNT * 64;   // 9.6M floats

    // d_out transient region (dead after place; x buffers reuse it):
    //   recs_bm: 6M int2 @ [0, 12M floats) | offM: 1465*1173 ints @ [12M, ~13.72M)
    int2* recs_bm = (int2*)out;
    int*  offM    = (int*)(out + 12000000);

    // workspace (~87.6 MB):
    char* ws = (char*)d_ws;
    float* acc   = (float*)ws;                                    // 9.6M floats
    int2*  pairs = (int2*)(ws + XB * 4);                          // 6M int2
    int*   cnt   = (int*)(ws + XB * 4 + (size_t)NNZ_CNT * 8);     // 150000
    int*   rp    = cnt + N_CNT;                                   // 150001 (+pad)
    int*   bsum  = rp + N_CNT + 4;                                // 1024
    int*   boff  = bsum + 1024;                                   // 1024

    float* xA = out;            // [0, 9.6M)
    float* xB = out + XB;       // [9.6M, 19.2M)

    // ---- build: bucket-sorted records -> row counts -> rp -> CSR pairs ----
    bin_sort_kernel<<<NBLK_BIN, 1024, 0, stream>>>(erow, ecol, evalv, recs_bm, offM);
    row_hist_kernel<<<NBKT, 1024, 0, stream>>>(recs_bm, offM, cnt);
    int nb = (N_CNT + 1023) / 1024;  // 147
    scan_block_kernel<<<nb, 1024, 0, stream>>>(cnt, rp, bsum, N_CNT);
    scan_block_kernel<<<1, 1024, 0, stream>>>(bsum, boff, nullptr, nb);
    scan_fix_kernel<<<nb, 1024, 0, stream>>>(rp, boff, N_CNT, NNZ_CNT);
    place_kernel<<<NBKT, 1024, 0, stream>>>(recs_bm, offM, rp, pairs);

    // ---- x0 = concat(user_emb, item_emb) (recs_bm/offM now dead) ----
    hipMemcpyAsync(xA, user_emb, (size_t)U_CNT * 64 * 4, hipMemcpyDeviceToDevice, stream);
    hipMemcpyAsync(xA + (size_t)U_CNT * 64, item_emb, (size_t)I_CNT * 64 * 4,
                   hipMemcpyDeviceToDevice, stream);

    // ---- 3 propagation layers ----
    int sg = N_CNT / 4;  // 37500
    spmm_kernel<<<sg, 256, 0, stream>>>(rp, pairs, xA, xB, acc, 0);
    spmm_kernel<<<sg, 256, 0, stream>>>(rp, pairs, xB, xA, acc, 1);
    spmm_kernel<<<sg, 256, 0, stream>>>(rp, pairs, xA, nullptr, acc, 2);

    // ---- fused MLP heads (shared + user / shared + item), overwrite d_out ----
    const float sc = 1.0f / 3.0f;
    mlp_dual_kernel<<<512, 256, 0, stream>>>(acc, 0, U_CNT, sc,
        Wsg1, bsg1, Wsg2, bsg2, Wuf1, buf1, Wuf2, buf2, out, out + XB);
    mlp_dual_kernel<<<512, 256, 0, stream>>>(acc, U_CNT, N_CNT, sc,
        Wsg1, bsg1, Wsg2, bsg2, Wif1, bif1, Wif2, bif2, out, out + XB);
}

// Round 9
// 1027.279 us; speedup vs baseline: 1.2142x; 1.2142x over previous
//
#include <hip/hip_runtime.h>
#include <hip/hip_bf16.h>

#define U_CNT 100000
#define I_CNT 50000
#define N_CNT 150000
#define NNZ_CNT 6000000
#define BKT_ROWS 128
#define NBKT 1172                 // ceil(150000/128)
#define OFFW (NBKT + 1)           // 1173
#define CHUNK 4096
#define NBLK_BIN 1465             // ceil(6M/4096)
#define COL_MASK 0x3FFFF          // 18 bits (N=150000 < 2^18)

typedef unsigned short ushort_t;

__device__ __forceinline__ ushort_t f2bf_rne(float f) {
    unsigned u = __float_as_uint(f);
    unsigned r = (u + 0x7FFFu + ((u >> 16) & 1u)) >> 16;
    return (ushort_t)r;
}
__device__ __forceinline__ float bf2f(ushort_t h) {
    return __uint_as_float((unsigned)h << 16);
}

// ---------------------------------------------------------------------------
// bin_sort: per-block LDS counting sort by bucket (row>>7); block-major
// write-once output (zero RMW amplification). offM[g][b] = segment starts.
// ---------------------------------------------------------------------------
__global__ __launch_bounds__(1024) void bin_sort_kernel(
    const int* __restrict__ erow, const int* __restrict__ ecol,
    const float* __restrict__ evalv,
    int2* __restrict__ recs_bm, int* __restrict__ offM)
{
    __shared__ int2 stage[CHUNK];       // 32 KB; low 8KB reused as scan temp
    __shared__ int  hist[NBKT];
    __shared__ int  lbase[NBKT];

    int t = threadIdx.x;
    int g = blockIdx.x;
    int base = g * CHUNK;
    int n = NNZ_CNT - base; if (n > CHUNK) n = CHUNK;

    int rows[4], cols[4]; float vals[4];
#pragma unroll
    for (int k = 0; k < 4; ++k) {
        int e = base + k * 1024 + t;
        bool ok = (e < NNZ_CNT);
        rows[k] = ok ? erow[e] : -1;
        cols[k] = ok ? ecol[e] : 0;
        vals[k] = ok ? evalv[e] : 0.f;
    }

    for (int i = t; i < NBKT; i += 1024) hist[i] = 0;
    __syncthreads();
#pragma unroll
    for (int k = 0; k < 4; ++k)
        if (rows[k] >= 0) atomicAdd(&hist[rows[k] >> 7], 1);
    __syncthreads();

    // exclusive scan of hist (2048-wide two-half Hillis in stage temp)
    int* sc = (int*)stage;
    int v0 = (t < NBKT) ? hist[t] : 0;
    int v1 = (1024 + t < NBKT) ? hist[1024 + t] : 0;
    sc[t] = v0; sc[1024 + t] = v1;
    __syncthreads();
    for (int off = 1; off < 1024; off <<= 1) {
        int u0 = (t >= off) ? sc[t - off] : 0;
        int u1 = (t >= off) ? sc[1024 + t - off] : 0;
        __syncthreads();
        sc[t] += u0; sc[1024 + t] += u1;
        __syncthreads();
    }
    int tot0 = sc[1023];
    if (t < NBKT) lbase[t] = sc[t] - v0;
    if (1024 + t < NBKT) lbase[1024 + t] = tot0 + sc[1024 + t] - v1;
    __syncthreads();

    for (int i = t; i < NBKT; i += 1024) hist[i] = 0;
    __syncthreads();

#pragma unroll
    for (int k = 0; k < 4; ++k) {
        if (rows[k] >= 0) {
            int b = rows[k] >> 7;
            int p = lbase[b] + atomicAdd(&hist[b], 1);
            int pack = ((rows[k] & (BKT_ROWS - 1)) << 18) | cols[k];
            stage[p] = make_int2(pack, __float_as_int(vals[k]));
        }
    }
    __syncthreads();

    for (int i = t; i < n; i += 1024) recs_bm[base + i] = stage[i];

    for (int i = t; i < NBKT; i += 1024)
        offM[(size_t)g * OFFW + i] = base + lbase[i];
    if (t == 0) offM[(size_t)g * OFFW + NBKT] = base + n;
}

// ---------------------------------------------------------------------------
// row_hist: block = bucket; count rows from block-major records (L2/L3 hits).
// ---------------------------------------------------------------------------
__global__ __launch_bounds__(1024) void row_hist_kernel(
    const int2* __restrict__ recs_bm, const int* __restrict__ offM,
    int* __restrict__ cnt)
{
    __shared__ int lcnt[BKT_ROWS];
    int b = blockIdx.x;
    int t = threadIdx.x;
    if (t < BKT_ROWS) lcnt[t] = 0;
    __syncthreads();
    int wid = t >> 6, lane = t & 63;
    for (int g = wid; g < NBLK_BIN; g += 16) {
        size_t o = (size_t)g * OFFW + b;
        int s = offM[o], e = offM[o + 1];
        for (int i = s + lane; i < e; i += 64)
            atomicAdd(&lcnt[recs_bm[i].x >> 18], 1);
    }
    __syncthreads();
    int rowbase = b << 7;
    if (t < BKT_ROWS && rowbase + t < N_CNT) cnt[rowbase + t] = lcnt[t];
}

// ---------------------------------------------------------------------------
// 2-level exclusive scan over row counts -> rp
// ---------------------------------------------------------------------------
__global__ void scan_block_kernel(const int* __restrict__ in, int* __restrict__ out,
                                  int* __restrict__ bsum, int n) {
    __shared__ int sm[1024];
    int t = threadIdx.x;
    int i = blockIdx.x * 1024 + t;
    int v = (i < n) ? in[i] : 0;
    sm[t] = v;
    __syncthreads();
    for (int off = 1; off < 1024; off <<= 1) {
        int u = (t >= off) ? sm[t - off] : 0;
        __syncthreads();
        sm[t] += u;
        __syncthreads();
    }
    if (i < n) out[i] = sm[t] - v;
    if (t == 1023 && bsum) bsum[blockIdx.x] = sm[1023];
}

__global__ void scan_fix_kernel(int* __restrict__ rp, const int* __restrict__ boff,
                                int n, int nnz) {
    int i = blockIdx.x * 1024 + threadIdx.x;
    if (i < n) rp[i] += boff[blockIdx.x];
    if (i == 0) rp[n] = nnz;
}

// ---------------------------------------------------------------------------
// place: block = bucket; LDS row cursors; pairs store PRE-SCALED bf16 byte
// offset (col<<7). Block-exclusive contiguous destination region.
// ---------------------------------------------------------------------------
__global__ __launch_bounds__(1024) void place_kernel(
    const int2* __restrict__ recs_bm, const int* __restrict__ offM,
    const int* __restrict__ rp, int2* __restrict__ pairs)
{
    __shared__ int cur[BKT_ROWS];
    int b = blockIdx.x;
    int t = threadIdx.x;
    int rowbase = b << 7;
    if (t < BKT_ROWS) cur[t] = (rowbase + t < N_CNT) ? rp[rowbase + t] : 0;
    __syncthreads();
    int wid = t >> 6, lane = t & 63;
    for (int g = wid; g < NBLK_BIN; g += 16) {
        size_t o = (size_t)g * OFFW + b;
        int s = offM[o], e = offM[o + 1];
        for (int i = s + lane; i < e; i += 64) {
            int2 r = recs_bm[i];
            int p = atomicAdd(&cur[r.x >> 18], 1);
            pairs[p] = make_int2((r.x & COL_MASK) << 7, r.y);  // bf16-row byte off
        }
    }
}

// ---------------------------------------------------------------------------
// cvt_concat: x0 = bf16(concat(user_emb, item_emb)). 8 elems/thread.
// ---------------------------------------------------------------------------
__global__ __launch_bounds__(256) void cvt_concat_kernel(
    const float* __restrict__ ue, const float* __restrict__ ie,
    ushort_t* __restrict__ x0)
{
    const size_t UE = (size_t)U_CNT * 64;   // 6.4M (divisible by 8)
    size_t i = ((size_t)blockIdx.x * 256 + threadIdx.x) * 8;
    if (i >= (size_t)N_CNT * 64) return;
    const float* src = (i < UE) ? (ue + i) : (ie + (i - UE));
    float4 a = *(const float4*)src;
    float4 b = *(const float4*)(src + 4);
    ushort_t o[8];
    o[0] = f2bf_rne(a.x); o[1] = f2bf_rne(a.y); o[2] = f2bf_rne(a.z); o[3] = f2bf_rne(a.w);
    o[4] = f2bf_rne(b.x); o[5] = f2bf_rne(b.y); o[6] = f2bf_rne(b.z); o[7] = f2bf_rne(b.w);
    *(uint4*)(x0 + i) = *(uint4*)o;
}

// ---------------------------------------------------------------------------
// SpMM: wave per row, lane = feature dim; bf16 gather (128B/edge), fp32 math.
// addr = x + (p.x | lane*2). mode: 0 = y & acc=, 1 = y & acc+=, 2 = acc+=.
// ---------------------------------------------------------------------------
__global__ __launch_bounds__(256) void spmm_kernel(
    const int* __restrict__ rp, const int2* __restrict__ pairs,
    const ushort_t* __restrict__ x, ushort_t* __restrict__ y,
    float* __restrict__ acc, int mode)
{
    int wave = threadIdx.x >> 6;
    int lane = threadIdx.x & 63;
    int row = blockIdx.x * 4 + wave;
    if (row >= N_CNT) return;
    int s = rp[row];
    int e = rp[row + 1];
    const char* xb = (const char*)x;
    unsigned lane2 = (unsigned)(lane << 1);
    float sum = 0.f;
    int i = s;
    for (; i + 7 < e; i += 8) {
        int2 p[8];
#pragma unroll
        for (int k = 0; k < 8; ++k) p[k] = pairs[i + k];
        ushort_t a[8];
#pragma unroll
        for (int k = 0; k < 8; ++k)
            a[k] = *(const ushort_t*)(xb + ((unsigned)p[k].x | lane2));
#pragma unroll
        for (int k = 0; k < 8; ++k)
            sum = fmaf(__int_as_float(p[k].y), bf2f(a[k]), sum);
    }
    for (; i < e; ++i) {
        int2 pk = pairs[i];
        sum = fmaf(__int_as_float(pk.y),
                   bf2f(*(const ushort_t*)(xb + ((unsigned)pk.x | lane2))), sum);
    }
    size_t o = (size_t)row * 64 + lane;
    if (mode == 0)      { y[o] = f2bf_rne(sum); acc[o] = sum; }
    else if (mode == 1) { y[o] = f2bf_rne(sum); acc[o] += sum; }
    else                {                       acc[o] += sum; }
}

// ---------------------------------------------------------------------------
// Fused dual 2-layer MLP. Weights in NATURAL row layout (h[lane] needs
// W[lane][k] contiguous -> no transpose), stride 68 pad -> conflict-free
// ds_read_b128. Reads acc once per row; writes both heads.
// ---------------------------------------------------------------------------
#define WST 68
__global__ __launch_bounds__(256) void mlp_dual_kernel(
    const float* __restrict__ acc, int row_s, int row_e, float scale,
    const float* __restrict__ Ws1, const float* __restrict__ bs1,
    const float* __restrict__ Ws2, const float* __restrict__ bs2,
    const float* __restrict__ Wx1, const float* __restrict__ bx1,
    const float* __restrict__ Wx2, const float* __restrict__ bx2,
    float* __restrict__ out_s, float* __restrict__ out_x)
{
    __shared__ float S1[64 * WST], S2[64 * WST], X1[64 * WST], X2[64 * WST];
    __shared__ float rbuf[4][64], h1buf[4][64], h2buf[4][64];

    int t = threadIdx.x;
    for (int idx = t; idx < 4096; idx += 256) {
        int d = idx >> 6, k = idx & 63;
        S1[d * WST + k] = Ws1[idx];
        S2[d * WST + k] = Ws2[idx];
        X1[d * WST + k] = Wx1[idx];
        X2[d * WST + k] = Wx2[idx];
    }
    __syncthreads();

    int wave = t >> 6, lane = t & 63;
    float vbs1 = bs1[lane], vbs2 = bs2[lane];
    float vbx1 = bx1[lane], vbx2 = bx2[lane];
    const float4* s1v = (const float4*)&S1[lane * WST];
    const float4* s2v = (const float4*)&S2[lane * WST];
    const float4* x1v = (const float4*)&X1[lane * WST];
    const float4* x2v = (const float4*)&X2[lane * WST];

    for (int r = row_s + blockIdx.x * 4 + wave; r < row_e; r += gridDim.x * 4) {
        float xv = acc[(size_t)r * 64 + lane] * scale;
        rbuf[wave][lane] = xv;           // same-wave produce/consume
        float h1 = vbs1, h2 = vbx1;
#pragma unroll
        for (int k4 = 0; k4 < 16; ++k4) {
            float4 rv = *(const float4*)&rbuf[wave][k4 * 4];   // broadcast
            float4 w1 = s1v[k4];
            float4 w2 = x1v[k4];
            h1 = fmaf(rv.x, w1.x, h1); h1 = fmaf(rv.y, w1.y, h1);
            h1 = fmaf(rv.z, w1.z, h1); h1 = fmaf(rv.w, w1.w, h1);
            h2 = fmaf(rv.x, w2.x, h2); h2 = fmaf(rv.y, w2.y, h2);
            h2 = fmaf(rv.z, w2.z, h2); h2 = fmaf(rv.w, w2.w, h2);
        }
        h1 = fmaxf(h1, 0.f);
        h2 = fmaxf(h2, 0.f);
        h1buf[wave][lane] = h1;
        h2buf[wave][lane] = h2;
        float y1 = vbs2, y2 = vbx2;
#pragma unroll
        for (int k4 = 0; k4 < 16; ++k4) {
            float4 a1 = *(const float4*)&h1buf[wave][k4 * 4];  // broadcast
            float4 a2 = *(const float4*)&h2buf[wave][k4 * 4];
            float4 w1 = s2v[k4];
            float4 w2 = x2v[k4];
            y1 = fmaf(a1.x, w1.x, y1); y1 = fmaf(a1.y, w1.y, y1);
            y1 = fmaf(a1.z, w1.z, y1); y1 = fmaf(a1.w, w1.w, y1);
            y2 = fmaf(a2.x, w2.x, y2); y2 = fmaf(a2.y, w2.y, y2);
            y2 = fmaf(a2.z, w2.z, y2); y2 = fmaf(a2.w, w2.w, y2);
        }
        out_s[(size_t)r * 64 + lane] = y1;
        out_x[(size_t)r * 64 + lane] = y2;
    }
}

// ---------------------------------------------------------------------------

static inline int imin(int a, int b) { return a < b ? a : b; }

extern "C" void kernel_launch(void* const* d_in, const int* in_sizes, int n_in,
                              void* d_out, int out_size, void* d_ws, size_t ws_size,
                              hipStream_t stream)
{
    (void)in_sizes; (void)n_in; (void)out_size; (void)ws_size;

    const float* user_emb = (const float*)d_in[0];
    const float* item_emb = (const float*)d_in[1];
    const int*   erow     = (const int*)d_in[2];
    const int*   ecol     = (const int*)d_in[3];
    const float* evalv    = (const float*)d_in[4];
    const float* Wsg1 = (const float*)d_in[5];
    const float* bsg1 = (const float*)d_in[6];
    const float* Wsg2 = (const float*)d_in[7];
    const float* bsg2 = (const float*)d_in[8];
    const float* Wuf1 = (const float*)d_in[9];
    const float* buf1 = (const float*)d_in[10];
    const float* Wuf2 = (const float*)d_in[11];
    const float* buf2 = (const float*)d_in[12];
    const float* Wif1 = (const float*)d_in[13];
    const float* bif1 = (const float*)d_in[14];
    const float* Wif2 = (const float*)d_in[15];
    const float* bif2 = (const float*)d_in[16];

    float* out = (float*)d_out;
    const size_t XB = (size_t)N_CNT * 64;   // 9.6M elements per node-buffer

    // d_out transient: recs_bm [0,12M floats) | offM [12M, ~13.72M) — dead
    // after place. Then bf16 x ping-pong: xA [0, 4.8M floats), xB [4.8M, 9.6M).
    // Both dead before MLP overwrites all of d_out.
    int2*     recs_bm = (int2*)out;
    int*      offM    = (int*)(out + 12000000);
    ushort_t* xA      = (ushort_t*)out;                    // 9.6M bf16
    ushort_t* xB      = (ushort_t*)(out + 4800000);        // 9.6M bf16

    // workspace (~87.6 MB):
    char* ws = (char*)d_ws;
    float* acc   = (float*)ws;                                    // 9.6M floats
    int2*  pairs = (int2*)(ws + XB * 4);                          // 6M int2
    int*   cnt   = (int*)(ws + XB * 4 + (size_t)NNZ_CNT * 8);     // 150000
    int*   rp    = cnt + N_CNT;                                   // 150001 (+pad)
    int*   bsum  = rp + N_CNT + 4;                                // 1024
    int*   boff  = bsum + 1024;                                   // 1024

    // ---- build: bucket-sorted records -> row counts -> rp -> CSR pairs ----
    bin_sort_kernel<<<NBLK_BIN, 1024, 0, stream>>>(erow, ecol, evalv, recs_bm, offM);
    row_hist_kernel<<<NBKT, 1024, 0, stream>>>(recs_bm, offM, cnt);
    int nb = (N_CNT + 1023) / 1024;  // 147
    scan_block_kernel<<<nb, 1024, 0, stream>>>(cnt, rp, bsum, N_CNT);
    scan_block_kernel<<<1, 1024, 0, stream>>>(bsum, boff, nullptr, nb);
    scan_fix_kernel<<<nb, 1024, 0, stream>>>(rp, boff, N_CNT, NNZ_CNT);
    place_kernel<<<NBKT, 1024, 0, stream>>>(recs_bm, offM, rp, pairs);

    // ---- x0 = bf16(concat(user_emb, item_emb)) (recs_bm/offM now dead) ----
    cvt_concat_kernel<<<(int)((XB / 8 + 255) / 256), 256, 0, stream>>>(user_emb, item_emb, xA);

    // ---- 3 propagation layers (bf16 gather, fp32 accumulate) ----
    int sg = N_CNT / 4;  // 37500
    spmm_kernel<<<sg, 256, 0, stream>>>(rp, pairs, xA, xB, acc, 0);
    spmm_kernel<<<sg, 256, 0, stream>>>(rp, pairs, xB, xA, acc, 1);
    spmm_kernel<<<sg, 256, 0, stream>>>(rp, pairs, xA, nullptr, acc, 2);

    // ---- fused MLP heads (shared + user / shared + item), overwrite d_out ----
    const float sc = 1.0f / 3.0f;
    mlp_dual_kernel<<<512, 256, 0, stream>>>(acc, 0, U_CNT, sc,
        Wsg1, bsg1, Wsg2, bsg2, Wuf1, buf1, Wuf2, buf2, out, out + XB);
    mlp_dual_kernel<<<512, 256, 0, stream>>>(acc, U_CNT, N_CNT, sc,
        Wsg1, bsg1, Wsg2, bsg2, Wif1, bif1, Wif2, bif2, out, out + XB);
}

// Round 10
// 767.048 us; speedup vs baseline: 1.6262x; 1.3393x over previous
//
#include <hip/hip_runtime.h>
#include <hip/hip_bf16.h>

#define U_CNT 100000
#define I_CNT 50000
#define N_CNT 150000
#define NNZ_CNT 6000000
#define BKT_ROWS 128
#define NBKT 1172                 // ceil(150000/128) buckets of 128 rows
#define OFFW (NBKT + 1)           // 1173
#define CHUNK 8192
#define NBLK_BIN 733              // ceil(6M/8192)
#define NGRP 147                  // ceil(150000/1024) groups of 8 buckets
#define COL_MASK 0x3FFFF          // 18 bits (N=150000 < 2^18)

typedef unsigned short ushort_t;

__device__ __forceinline__ ushort_t f2bf_rne(float f) {
    unsigned u = __float_as_uint(f);
    unsigned r = (u + 0x7FFFu + ((u >> 16) & 1u)) >> 16;
    return (ushort_t)r;
}
__device__ __forceinline__ float bf2f(ushort_t h) {
    return __uint_as_float((unsigned)h << 16);
}

// ---------------------------------------------------------------------------
// bin_sort: per-block LDS counting sort by bucket (row>>7), CHUNK=8192.
// Two-pass (re-reads erow) to keep VGPRs low. Output block-major, write-once.
// Record pack: ((row & 16383) << 18) | col  -> consumers get group-local row.
// Also accumulates per-group (8-bucket) counts for the global row-base scan.
// ---------------------------------------------------------------------------
__global__ __launch_bounds__(1024) void bin_sort_kernel(
    const int* __restrict__ erow, const int* __restrict__ ecol,
    const float* __restrict__ evalv,
    int2* __restrict__ recs_bm, int* __restrict__ offM, int* __restrict__ gcnt)
{
    __shared__ int2 stage[CHUNK];       // 64 KB; low 8 KB reused as scan temp
    __shared__ int  hist[NBKT];
    __shared__ int  lbase[NBKT];

    int t = threadIdx.x;
    int g = blockIdx.x;
    int base = g * CHUNK;
    int n = NNZ_CNT - base; if (n > CHUNK) n = CHUNK;

    for (int i = t; i < NBKT; i += 1024) hist[i] = 0;
    __syncthreads();

    // pass A: bucket histogram
#pragma unroll
    for (int k = 0; k < 8; ++k) {
        int e = base + k * 1024 + t;
        if (e < NNZ_CNT) atomicAdd(&hist[erow[e] >> 7], 1);
    }
    __syncthreads();

    // per-group global counts (8 buckets per group)
    for (int i = t; i < NGRP; i += 1024) {
        int s = 0;
#pragma unroll
        for (int j = 0; j < 8; ++j) {
            int b = i * 8 + j;
            if (b < NBKT) s += hist[b];
        }
        if (s) atomicAdd(&gcnt[i], s);
    }

    // exclusive scan of hist (2048-wide two-half Hillis in stage temp)
    int* sc = (int*)stage;
    int v0 = (t < NBKT) ? hist[t] : 0;
    int v1 = (1024 + t < NBKT) ? hist[1024 + t] : 0;
    sc[t] = v0; sc[1024 + t] = v1;
    __syncthreads();
    for (int off = 1; off < 1024; off <<= 1) {
        int u0 = (t >= off) ? sc[t - off] : 0;
        int u1 = (t >= off) ? sc[1024 + t - off] : 0;
        __syncthreads();
        sc[t] += u0; sc[1024 + t] += u1;
        __syncthreads();
    }
    int tot0 = sc[1023];
    if (t < NBKT) lbase[t] = sc[t] - v0;
    if (1024 + t < NBKT) lbase[1024 + t] = tot0 + sc[1024 + t] - v1;
    __syncthreads();

    // reset hist as scatter cursors
    for (int i = t; i < NBKT; i += 1024) hist[i] = 0;
    __syncthreads();

    // pass B: re-read edges, scatter into LDS stage (bucket-major in block)
#pragma unroll
    for (int k = 0; k < 8; ++k) {
        int e = base + k * 1024 + t;
        if (e < NNZ_CNT) {
            int r = erow[e];
            int c = ecol[e];
            float v = evalv[e];
            int b = r >> 7;
            int p = lbase[b] + atomicAdd(&hist[b], 1);
            stage[p] = make_int2(((r & 16383) << 18) | c, __float_as_int(v));
        }
    }
    __syncthreads();

    // stream out block's private region (coalesced, full lines, write-once)
    for (int i = t; i < n; i += 1024) recs_bm[base + i] = stage[i];

    // per-block bucket offsets
    for (int i = t; i < NBKT; i += 1024)
        offM[(size_t)g * OFFW + i] = base + lbase[i];
    if (t == 0) offM[(size_t)g * OFFW + NBKT] = base + n;
}

// ---------------------------------------------------------------------------
// gscan: exclusive scan of gcnt[147] -> gbase; writes rp[N] sentinel.
// ---------------------------------------------------------------------------
__global__ __launch_bounds__(256) void gscan_kernel(
    const int* __restrict__ gcnt, int* __restrict__ gbase, int* __restrict__ rp)
{
    __shared__ int sm[256];
    int t = threadIdx.x;
    int v = (t < NGRP) ? gcnt[t] : 0;
    sm[t] = v;
    __syncthreads();
    for (int off = 1; off < 256; off <<= 1) {
        int u = (t >= off) ? sm[t - off] : 0;
        __syncthreads();
        sm[t] += u;
        __syncthreads();
    }
    if (t < NGRP) gbase[t] = sm[t] - v;
    if (t == 0) rp[N_CNT] = NNZ_CNT;
}

// ---------------------------------------------------------------------------
// build_csr: block = group of 8 buckets (1024 rows). Per source block g the
// group's records are CONTIGUOUS: [offM[g][b0], offM[g][min(b0+8,NBKT)]) —
// avg 56 records = 448B -> ~1.14x read amp, ~87% lane utilization.
// Phase 1: LDS row histogram. Phase 2: LDS scan + gbase -> rp + cursors.
// Phase 3: replay segments, place pairs (pre-scaled bf16 byte offsets).
// ---------------------------------------------------------------------------
__global__ __launch_bounds__(1024) void build_csr_kernel(
    const int2* __restrict__ recs_bm, const int* __restrict__ offM,
    const int* __restrict__ gbase, int* __restrict__ rp, int2* __restrict__ pairs)
{
    __shared__ int lcnt[1024];
    __shared__ int cur[1024];
    int t = threadIdx.x;
    int blk = blockIdx.x;
    int b0 = blk * 8;
    int bend = b0 + 8; if (bend > NBKT) bend = NBKT;

    lcnt[t] = 0;
    __syncthreads();

    int wid = t >> 6, lane = t & 63;

    // phase 1: row histogram
    for (int g = wid; g < NBLK_BIN; g += 16) {
        size_t o = (size_t)g * OFFW;
        int s = offM[o + b0], e = offM[o + bend];
        for (int i = s + lane; i < e; i += 64) {
            unsigned px = (unsigned)recs_bm[i].x;
            atomicAdd(&lcnt[(px >> 18) & 1023], 1);
        }
    }
    __syncthreads();

    // phase 2: exclusive scan + global base -> cursors, write rp
    int v = lcnt[t];
    __syncthreads();
    for (int off = 1; off < 1024; off <<= 1) {
        int u = (t >= off) ? lcnt[t - off] : 0;
        __syncthreads();
        lcnt[t] += u;
        __syncthreads();
    }
    int abs0 = gbase[blk] + lcnt[t] - v;   // exclusive + base
    cur[t] = abs0;
    int row = blk * 1024 + t;
    if (row < N_CNT) rp[row] = abs0;
    __syncthreads();

    // phase 3: place records
    for (int g = wid; g < NBLK_BIN; g += 16) {
        size_t o = (size_t)g * OFFW;
        int s = offM[o + b0], e = offM[o + bend];
        for (int i = s + lane; i < e; i += 64) {
            int2 rec = recs_bm[i];
            unsigned px = (unsigned)rec.x;
            int p = atomicAdd(&cur[(px >> 18) & 1023], 1);
            pairs[p] = make_int2((int)((px & COL_MASK) << 7), rec.y);
        }
    }
}

// ---------------------------------------------------------------------------
// cvt_concat: x0 = bf16(concat(user_emb, item_emb)). 8 elems/thread.
// ---------------------------------------------------------------------------
__global__ __launch_bounds__(256) void cvt_concat_kernel(
    const float* __restrict__ ue, const float* __restrict__ ie,
    ushort_t* __restrict__ x0)
{
    const size_t UE = (size_t)U_CNT * 64;   // 6.4M (divisible by 8)
    size_t i = ((size_t)blockIdx.x * 256 + threadIdx.x) * 8;
    if (i >= (size_t)N_CNT * 64) return;
    const float* src = (i < UE) ? (ue + i) : (ie + (i - UE));
    float4 a = *(const float4*)src;
    float4 b = *(const float4*)(src + 4);
    ushort_t o[8];
    o[0] = f2bf_rne(a.x); o[1] = f2bf_rne(a.y); o[2] = f2bf_rne(a.z); o[3] = f2bf_rne(a.w);
    o[4] = f2bf_rne(b.x); o[5] = f2bf_rne(b.y); o[6] = f2bf_rne(b.z); o[7] = f2bf_rne(b.w);
    *(uint4*)(x0 + i) = *(uint4*)o;
}

// ---------------------------------------------------------------------------
// SpMM: wave per row, lane = feature dim; bf16 gather (128B/edge), fp32 math.
// addr = x + (p.x | lane*2). mode: 0 = y & acc=, 1 = y & acc+=, 2 = acc+=.
// ---------------------------------------------------------------------------
__global__ __launch_bounds__(256) void spmm_kernel(
    const int* __restrict__ rp, const int2* __restrict__ pairs,
    const ushort_t* __restrict__ x, ushort_t* __restrict__ y,
    float* __restrict__ acc, int mode)
{
    int wave = threadIdx.x >> 6;
    int lane = threadIdx.x & 63;
    int row = blockIdx.x * 4 + wave;
    if (row >= N_CNT) return;
    int s = rp[row];
    int e = rp[row + 1];
    const char* xb = (const char*)x;
    unsigned lane2 = (unsigned)(lane << 1);
    float sum = 0.f;
    int i = s;
    for (; i + 7 < e; i += 8) {
        int2 p[8];
#pragma unroll
        for (int k = 0; k < 8; ++k) p[k] = pairs[i + k];
        ushort_t a[8];
#pragma unroll
        for (int k = 0; k < 8; ++k)
            a[k] = *(const ushort_t*)(xb + ((unsigned)p[k].x | lane2));
#pragma unroll
        for (int k = 0; k < 8; ++k)
            sum = fmaf(__int_as_float(p[k].y), bf2f(a[k]), sum);
    }
    for (; i < e; ++i) {
        int2 pk = pairs[i];
        sum = fmaf(__int_as_float(pk.y),
                   bf2f(*(const ushort_t*)(xb + ((unsigned)pk.x | lane2))), sum);
    }
    size_t o = (size_t)row * 64 + lane;
    if (mode == 0)      { y[o] = f2bf_rne(sum); acc[o] = sum; }
    else if (mode == 1) { y[o] = f2bf_rne(sum); acc[o] += sum; }
    else                {                       acc[o] += sum; }
}

// ---------------------------------------------------------------------------
// Fused dual 2-layer MLP. Natural row layout, stride-68 pad, float4 reads.
// ---------------------------------------------------------------------------
#define WST 68
__global__ __launch_bounds__(256) void mlp_dual_kernel(
    const float* __restrict__ acc, int row_s, int row_e, float scale,
    const float* __restrict__ Ws1, const float* __restrict__ bs1,
    const float* __restrict__ Ws2, const float* __restrict__ bs2,
    const float* __restrict__ Wx1, const float* __restrict__ bx1,
    const float* __restrict__ Wx2, const float* __restrict__ bx2,
    float* __restrict__ out_s, float* __restrict__ out_x)
{
    __shared__ float S1[64 * WST], S2[64 * WST], X1[64 * WST], X2[64 * WST];
    __shared__ float rbuf[4][64], h1buf[4][64], h2buf[4][64];

    int t = threadIdx.x;
    for (int idx = t; idx < 4096; idx += 256) {
        int d = idx >> 6, k = idx & 63;
        S1[d * WST + k] = Ws1[idx];
        S2[d * WST + k] = Ws2[idx];
        X1[d * WST + k] = Wx1[idx];
        X2[d * WST + k] = Wx2[idx];
    }
    __syncthreads();

    int wave = t >> 6, lane = t & 63;
    float vbs1 = bs1[lane], vbs2 = bs2[lane];
    float vbx1 = bx1[lane], vbx2 = bx2[lane];
    const float4* s1v = (const float4*)&S1[lane * WST];
    const float4* s2v = (const float4*)&S2[lane * WST];
    const float4* x1v = (const float4*)&X1[lane * WST];
    const float4* x2v = (const float4*)&X2[lane * WST];

    for (int r = row_s + blockIdx.x * 4 + wave; r < row_e; r += gridDim.x * 4) {
        float xv = acc[(size_t)r * 64 + lane] * scale;
        rbuf[wave][lane] = xv;           // same-wave produce/consume
        float h1 = vbs1, h2 = vbx1;
#pragma unroll
        for (int k4 = 0; k4 < 16; ++k4) {
            float4 rv = *(const float4*)&rbuf[wave][k4 * 4];
            float4 w1 = s1v[k4];
            float4 w2 = x1v[k4];
            h1 = fmaf(rv.x, w1.x, h1); h1 = fmaf(rv.y, w1.y, h1);
            h1 = fmaf(rv.z, w1.z, h1); h1 = fmaf(rv.w, w1.w, h1);
            h2 = fmaf(rv.x, w2.x, h2); h2 = fmaf(rv.y, w2.y, h2);
            h2 = fmaf(rv.z, w2.z, h2); h2 = fmaf(rv.w, w2.w, h2);
        }
        h1 = fmaxf(h1, 0.f);
        h2 = fmaxf(h2, 0.f);
        h1buf[wave][lane] = h1;
        h2buf[wave][lane] = h2;
        float y1 = vbs2, y2 = vbx2;
#pragma unroll
        for (int k4 = 0; k4 < 16; ++k4) {
            float4 a1 = *(const float4*)&h1buf[wave][k4 * 4];
            float4 a2 = *(const float4*)&h2buf[wave][k4 * 4];
            float4 w1 = s2v[k4];
            float4 w2 = x2v[k4];
            y1 = fmaf(a1.x, w1.x, y1); y1 = fmaf(a1.y, w1.y, y1);
            y1 = fmaf(a1.z, w1.z, y1); y1 = fmaf(a1.w, w1.w, y1);
            y2 = fmaf(a2.x, w2.x, y2); y2 = fmaf(a2.y, w2.y, y2);
            y2 = fmaf(a2.z, w2.z, y2); y2 = fmaf(a2.w, w2.w, y2);
        }
        out_s[(size_t)r * 64 + lane] = y1;
        out_x[(size_t)r * 64 + lane] = y2;
    }
}

// ---------------------------------------------------------------------------

extern "C" void kernel_launch(void* const* d_in, const int* in_sizes, int n_in,
                              void* d_out, int out_size, void* d_ws, size_t ws_size,
                              hipStream_t stream)
{
    (void)in_sizes; (void)n_in; (void)out_size; (void)ws_size;

    const float* user_emb = (const float*)d_in[0];
    const float* item_emb = (const float*)d_in[1];
    const int*   erow     = (const int*)d_in[2];
    const int*   ecol     = (const int*)d_in[3];
    const float* evalv    = (const float*)d_in[4];
    const float* Wsg1 = (const float*)d_in[5];
    const float* bsg1 = (const float*)d_in[6];
    const float* Wsg2 = (const float*)d_in[7];
    const float* bsg2 = (const float*)d_in[8];
    const float* Wuf1 = (const float*)d_in[9];
    const float* buf1 = (const float*)d_in[10];
    const float* Wuf2 = (const float*)d_in[11];
    const float* buf2 = (const float*)d_in[12];
    const float* Wif1 = (const float*)d_in[13];
    const float* bif1 = (const float*)d_in[14];
    const float* Wif2 = (const float*)d_in[15];
    const float* bif2 = (const float*)d_in[16];

    float* out = (float*)d_out;
    const size_t XB = (size_t)N_CNT * 64;   // 9.6M elements per node-buffer

    // d_out transient: recs_bm 48MB @ [0,12M floats) | offM 3.44MB @ [12M, ...)
    // Dead after build_csr; then bf16 x ping-pong xA/xB reuse the same space.
    int2*     recs_bm = (int2*)out;
    int*      offM    = (int*)(out + 12000000);
    ushort_t* xA      = (ushort_t*)out;                    // 9.6M bf16
    ushort_t* xB      = (ushort_t*)(out + 4800000);        // 9.6M bf16

    // workspace (~87 MB):
    char* ws = (char*)d_ws;
    float* acc   = (float*)ws;                                    // 9.6M floats
    int2*  pairs = (int2*)(ws + XB * 4);                          // 6M int2
    int*   rp    = (int*)(ws + XB * 4 + (size_t)NNZ_CNT * 8);     // N+1 (+pad)
    int*   gcnt  = rp + N_CNT + 8;                                // 160
    int*   gbase = gcnt + 160;                                    // 160

    // ---- build: bin (8K chunks) -> group scan -> fused hist/scan/place ----
    hipMemsetAsync(gcnt, 0, NGRP * sizeof(int), stream);
    bin_sort_kernel<<<NBLK_BIN, 1024, 0, stream>>>(erow, ecol, evalv, recs_bm, offM, gcnt);
    gscan_kernel<<<1, 256, 0, stream>>>(gcnt, gbase, rp);
    build_csr_kernel<<<NGRP, 1024, 0, stream>>>(recs_bm, offM, gbase, rp, pairs);

    // ---- x0 = bf16(concat(user_emb, item_emb)) (recs_bm/offM now dead) ----
    cvt_concat_kernel<<<(int)((XB / 8 + 255) / 256), 256, 0, stream>>>(user_emb, item_emb, xA);

    // ---- 3 propagation layers (bf16 gather, fp32 accumulate) ----
    int sg = N_CNT / 4;  // 37500
    spmm_kernel<<<sg, 256, 0, stream>>>(rp, pairs, xA, xB, acc, 0);
    spmm_kernel<<<sg, 256, 0, stream>>>(rp, pairs, xB, xA, acc, 1);
    spmm_kernel<<<sg, 256, 0, stream>>>(rp, pairs, xA, nullptr, acc, 2);

    // ---- fused MLP heads (shared + user / shared + item), overwrite d_out ----
    const float sc = 1.0f / 3.0f;
    mlp_dual_kernel<<<512, 256, 0, stream>>>(acc, 0, U_CNT, sc,
        Wsg1, bsg1, Wsg2, bsg2, Wuf1, buf1, Wuf2, buf2, out, out + XB);
    mlp_dual_kernel<<<512, 256, 0, stream>>>(acc, U_CNT, N_CNT, sc,
        Wsg1, bsg1, Wsg2, bsg2, Wif1, bif1, Wif2, bif2, out, out + XB);
}